// Round 1
// baseline (77.665 us; speedup 1.0000x reference)
//
#include <hip/hip_runtime.h>

#define H 256
#define SEQ 2048
#define NBATCH 64
#define M_TOTAL (NBATCH * SEQ)   // 131072 rows
#define BM 64                    // rows per block

using bf16x8 = __attribute__((ext_vector_type(8))) short;
using u16x4  = __attribute__((ext_vector_type(4))) unsigned short;
using f32x4  = __attribute__((ext_vector_type(4))) float;

__device__ __forceinline__ unsigned short f2bf(float x) {
    union { float f; unsigned u; } v; v.f = x;
    unsigned r = v.u + 0x7fffu + ((v.u >> 16) & 1u);   // RNE
    return (unsigned short)(r >> 16);
}
__device__ __forceinline__ float bf2f(unsigned short b) {
    union { unsigned u; float f; } v; v.u = ((unsigned)b) << 16;
    return v.f;
}

// ---------------- prep 1: qpb[d] = sum_c q[c]*W2[c,d] + b1[d] + b2[d] ----------------
__global__ __launch_bounds__(256) void prep_qpb(const float* __restrict__ q,
                                                const float* __restrict__ W2,
                                                const float* __restrict__ b1,
                                                const float* __restrict__ b2,
                                                float* __restrict__ qpb) {
    int t = threadIdx.x;
    float s = 0.f;
#pragma unroll 8
    for (int c = 0; c < H; ++c) s = fmaf(q[c], W2[c * H + t], s);
    qpb[t] = s + b1[t] + b2[t];
}

// ---------------- prep 2: pack W1 into bf16 hi/lo MFMA B-fragment order --------------
// Layout (f16x8-granules): frag(ct 0..15, ks 0..7, h 0..1)[lane 0..63] of 8 bf16:
//   element j: W1split[h][k = ks*32 + (lane>>4)*8 + j][n = ct*16 + (lane&15)]
__global__ __launch_bounds__(256) void prep_bpack(const float* __restrict__ W1,
                                                  unsigned short* __restrict__ Bpack) {
    int tid = blockIdx.x * 256 + threadIdx.x;  // 0..8191 = (ct,ks,lane)
    int ct = tid >> 9;
    int ks = (tid >> 6) & 7;
    int l  = tid & 63;
    bf16x8 hi, lo;
#pragma unroll
    for (int j = 0; j < 8; ++j) {
        int kk = ks * 32 + ((l >> 4) & 3) * 8 + j;
        int nn = ct * 16 + (l & 15);
        float w = W1[kk * H + nn];
        unsigned short h = f2bf(w);
        float rem = w - bf2f(h);
        hi[j] = (short)h;
        lo[j] = (short)f2bf(rem);
    }
    bf16x8* out = (bf16x8*)Bpack;
    out[((ct * 8 + ks) * 2 + 0) * 64 + l] = hi;
    out[((ct * 8 + ks) * 2 + 1) * 64 + l] = lo;
}

// ---------------- main: scores[m] = sum_d tanh(k@W1 + qpb)[m,d] * V[d] ----------------
__global__ __launch_bounds__(256, 2) void fused_main(const float* __restrict__ kin,
                                                     const unsigned short* __restrict__ Bpack,
                                                     const float* __restrict__ qpb,
                                                     const float* __restrict__ Vp,
                                                     float* __restrict__ out_scores) {
    // LDS: A_hi [64 rows][256 k] bf16 (32 KB) + A_lo (32 KB), XOR-swizzled
    __shared__ __align__(16) unsigned char lds[65536];
    unsigned char* Ahi = lds;
    unsigned char* Alo = lds + 32768;

    const int t  = threadIdx.x;
    const int m0 = blockIdx.x * BM;

    // ---- stage k tile: f32 -> bf16 hi/lo into LDS ----
#pragma unroll
    for (int i = 0; i < 16; ++i) {
        int flat = i * 1024 + t * 4;          // covers [64][256]
        int r = flat >> 8;
        int c = flat & 255;
        const float4 v = *(const float4*)(kin + (m0 + r) * H + c);
        unsigned short h0 = f2bf(v.x), h1 = f2bf(v.y), h2 = f2bf(v.z), h3 = f2bf(v.w);
        u16x4 hi = {h0, h1, h2, h3};
        u16x4 lo = {f2bf(v.x - bf2f(h0)), f2bf(v.y - bf2f(h1)),
                    f2bf(v.z - bf2f(h2)), f2bf(v.w - bf2f(h3))};
        int addr = (r * 512 + c * 2) ^ ((r & 7) << 4);
        *(u16x4*)(Ahi + addr) = hi;
        *(u16x4*)(Alo + addr) = lo;
    }
    __syncthreads();

    const int wave = t >> 6;
    const int lane = t & 63;
    const int lhi  = lane >> 4;   // 0..3
    const int llo  = lane & 15;   // 0..15

    f32x4 acc[4][4];   // [rt][ct]
#pragma unroll
    for (int a = 0; a < 4; ++a)
#pragma unroll
        for (int b = 0; b < 4; ++b) acc[a][b] = (f32x4){0.f, 0.f, 0.f, 0.f};

    const bf16x8* Bp = (const bf16x8*)Bpack;

    for (int ks = 0; ks < 8; ++ks) {
        bf16x8 b_hi[4], b_lo[4], a_hi[4], a_lo[4];
#pragma unroll
        for (int ct = 0; ct < 4; ++ct) {
            int ctg = wave * 4 + ct;
            b_hi[ct] = Bp[((ctg * 8 + ks) * 2 + 0) * 64 + lane];
            b_lo[ct] = Bp[((ctg * 8 + ks) * 2 + 1) * 64 + lane];
        }
#pragma unroll
        for (int rt = 0; rt < 4; ++rt) {
            int r = rt * 16 + llo;                       // block-local row 0..63
            int byte = (r * 512 + ks * 64 + lhi * 16) ^ ((r & 7) << 4);
            a_hi[rt] = *(const bf16x8*)(Ahi + byte);
            a_lo[rt] = *(const bf16x8*)(Alo + byte);
        }
#pragma unroll
        for (int rt = 0; rt < 4; ++rt)
#pragma unroll
            for (int ct = 0; ct < 4; ++ct) {
                acc[rt][ct] = __builtin_amdgcn_mfma_f32_16x16x32_bf16(a_hi[rt], b_hi[ct], acc[rt][ct], 0, 0, 0);
                acc[rt][ct] = __builtin_amdgcn_mfma_f32_16x16x32_bf16(a_hi[rt], b_lo[ct], acc[rt][ct], 0, 0, 0);
                acc[rt][ct] = __builtin_amdgcn_mfma_f32_16x16x32_bf16(a_lo[rt], b_hi[ct], acc[rt][ct], 0, 0, 0);
            }
    }

    // ---- epilogue: tanh, *V, reduce over 256 cols ----
    float s[4][4];
#pragma unroll
    for (int a = 0; a < 4; ++a)
#pragma unroll
        for (int b = 0; b < 4; ++b) s[a][b] = 0.f;

#pragma unroll
    for (int ct = 0; ct < 4; ++ct) {
        int n = wave * 64 + ct * 16 + llo;   // global col (== C-frag col: lane&15)
        float qv = qpb[n];
        float vv = Vp[n];
#pragma unroll
        for (int rt = 0; rt < 4; ++rt)
#pragma unroll
            for (int i = 0; i < 4; ++i) {
                float x = acc[rt][ct][i] + qv;
                float e = __expf(2.f * x);
                float th = 1.f - 2.f * __builtin_amdgcn_rcpf(e + 1.f);
                s[rt][i] += th * vv;
            }
    }
    // reduce across the 16 column-lanes of each group
#pragma unroll
    for (int rt = 0; rt < 4; ++rt)
#pragma unroll
        for (int i = 0; i < 4; ++i) {
            float r = s[rt][i];
#pragma unroll
            for (int mask = 1; mask < 16; mask <<= 1) r += __shfl_xor(r, mask, 16);
            s[rt][i] = r;   // full sum over this wave's 64 cols, row rt*16+lhi*4+i
        }

    __syncthreads();                 // done with A region; reuse as partial buffer
    float* part = (float*)lds;       // [4 waves][64 rows]
    if (llo == 0) {
#pragma unroll
        for (int rt = 0; rt < 4; ++rt)
#pragma unroll
            for (int i = 0; i < 4; ++i)
                part[wave * 64 + rt * 16 + lhi * 4 + i] = s[rt][i];
    }
    __syncthreads();
    if (t < BM)
        out_scores[m0 + t] = part[t] + part[64 + t] + part[128 + t] + part[192 + t];
}

// ---------------- softmax over seq axis, in-place on d_out ----------------
__global__ __launch_bounds__(256) void softmax_kernel(float* __restrict__ out) {
    const int b = blockIdx.x;
    const int t = threadIdx.x;
    float* row = out + b * SEQ;
    float v[8];
#pragma unroll
    for (int j = 0; j < 8; ++j) v[j] = row[t + j * 256];
    float mx = v[0];
#pragma unroll
    for (int j = 1; j < 8; ++j) mx = fmaxf(mx, v[j]);
#pragma unroll
    for (int off = 1; off < 64; off <<= 1) mx = fmaxf(mx, __shfl_xor(mx, off, 64));
    __shared__ float redm[4], reds[4];
    int lane = t & 63, w = t >> 6;
    if (lane == 0) redm[w] = mx;
    __syncthreads();
    mx = fmaxf(fmaxf(redm[0], redm[1]), fmaxf(redm[2], redm[3]));
    float e[8], sum = 0.f;
#pragma unroll
    for (int j = 0; j < 8; ++j) { e[j] = __expf(v[j] - mx); sum += e[j]; }
#pragma unroll
    for (int off = 1; off < 64; off <<= 1) sum += __shfl_xor(sum, off, 64);
    if (lane == 0) reds[w] = sum;
    __syncthreads();
    float inv = 1.0f / (reds[0] + reds[1] + reds[2] + reds[3]);
#pragma unroll
    for (int j = 0; j < 8; ++j) row[t + j * 256] = e[j] * inv;
}

extern "C" void kernel_launch(void* const* d_in, const int* in_sizes, int n_in,
                              void* d_out, int out_size, void* d_ws, size_t ws_size,
                              hipStream_t stream) {
    const float* q  = (const float*)d_in[0];
    const float* k  = (const float*)d_in[1];
    const float* W1 = (const float*)d_in[2];
    const float* b1 = (const float*)d_in[3];
    const float* W2 = (const float*)d_in[4];
    const float* b2 = (const float*)d_in[5];
    const float* V  = (const float*)d_in[6];
    // d_in[7] = bv: scalar added to every score -> softmax-invariant, skipped.
    float* out = (float*)d_out;

    float* qpb = (float*)d_ws;                                   // 1 KB
    unsigned short* Bpack = (unsigned short*)((char*)d_ws + 1024); // 256 KB

    prep_qpb<<<1, 256, 0, stream>>>(q, W2, b1, b2, qpb);
    prep_bpack<<<32, 256, 0, stream>>>(W1, Bpack);
    fused_main<<<M_TOTAL / BM, 256, 0, stream>>>(k, Bpack, qpb, V, out);
    softmax_kernel<<<NBATCH, 256, 0, stream>>>(out);
}

// Round 2
// 76.886 us; speedup vs baseline: 1.0101x; 1.0101x over previous
//
#include <hip/hip_runtime.h>

#define H 256
#define SEQ 2048
#define NBATCH 64
#define M_TOTAL (NBATCH * SEQ)   // 131072 rows
#define BM 64                    // rows per block

using bf16x8 = __attribute__((ext_vector_type(8))) short;
using u16x4  = __attribute__((ext_vector_type(4))) unsigned short;
using f32x4  = __attribute__((ext_vector_type(4))) float;

__device__ __forceinline__ unsigned short f2bf(float x) {
    union { float f; unsigned u; } v; v.f = x;
    unsigned r = v.u + 0x7fffu + ((v.u >> 16) & 1u);   // RNE
    return (unsigned short)(r >> 16);
}
__device__ __forceinline__ float bf2f(unsigned short b) {
    union { unsigned u; float f; } v; v.u = ((unsigned)b) << 16;
    return v.f;
}

// ---------------- prep 1: qpb[d] = sum_c q[c]*W2[c,d] + b1[d] + b2[d] ----------------
__global__ __launch_bounds__(256) void prep_qpb(const float* __restrict__ q,
                                                const float* __restrict__ W2,
                                                const float* __restrict__ b1,
                                                const float* __restrict__ b2,
                                                float* __restrict__ qpb) {
    int t = threadIdx.x;
    float s = 0.f;
#pragma unroll 8
    for (int c = 0; c < H; ++c) s = fmaf(q[c], W2[c * H + t], s);
    qpb[t] = s + b1[t] + b2[t];
}

// ---------------- prep 2: pack W1 into bf16 hi/lo MFMA B-fragment order --------------
// Layout (bf16x8-granules): frag(ct 0..15, ks 0..7, h 0..1)[lane 0..63]:
//   element j: W1split[h][k = ks*32 + (lane>>4)*8 + j][n = ct*16 + (lane&15)]
__global__ __launch_bounds__(256) void prep_bpack(const float* __restrict__ W1,
                                                  unsigned short* __restrict__ Bpack) {
    int tid = blockIdx.x * 256 + threadIdx.x;  // 0..8191 = (ct,ks,lane)
    int ct = tid >> 9;
    int ks = (tid >> 6) & 7;
    int l  = tid & 63;
    bf16x8 hi, lo;
#pragma unroll
    for (int j = 0; j < 8; ++j) {
        int kk = ks * 32 + ((l >> 4) & 3) * 8 + j;
        int nn = ct * 16 + (l & 15);
        float w = W1[kk * H + nn];
        unsigned short h = f2bf(w);
        float rem = w - bf2f(h);
        hi[j] = (short)h;
        lo[j] = (short)f2bf(rem);
    }
    bf16x8* out = (bf16x8*)Bpack;
    out[((ct * 8 + ks) * 2 + 0) * 64 + l] = hi;
    out[((ct * 8 + ks) * 2 + 1) * 64 + l] = lo;
}

// ---------------- main: scores[m] = sum_d tanh(k@W1 + qpb)[m,d] * V[d] ----------------
// 512 threads = 8 waves; each wave owns 64 rows x 32 cols (rt=4, ct=2).
// LDS 64KB -> 2 blocks/CU -> 16 waves/CU = 4/SIMD (50% occupancy).
__global__ __launch_bounds__(512, 4) void fused_main(const float* __restrict__ kin,
                                                     const unsigned short* __restrict__ Bpack,
                                                     const float* __restrict__ qpb,
                                                     const float* __restrict__ Vp,
                                                     float* __restrict__ out_scores) {
    // LDS: A_hi [64 rows][256 k] bf16 (32 KB) + A_lo (32 KB), XOR-swizzled
    __shared__ __align__(16) unsigned char lds[65536];
    unsigned char* Ahi = lds;
    unsigned char* Alo = lds + 32768;

    const int t  = threadIdx.x;          // 0..511
    const int m0 = blockIdx.x * BM;

    // ---- stage k tile: f32 -> bf16 hi/lo into LDS (128B global per thread) ----
#pragma unroll
    for (int i = 0; i < 8; ++i) {
        int flat = i * 2048 + t * 4;      // covers [64][256] floats
        int r = flat >> 8;
        int c = flat & 255;
        const float4 v = *(const float4*)(kin + (m0 + r) * H + c);
        unsigned short h0 = f2bf(v.x), h1 = f2bf(v.y), h2 = f2bf(v.z), h3 = f2bf(v.w);
        u16x4 hi = {h0, h1, h2, h3};
        u16x4 lo = {f2bf(v.x - bf2f(h0)), f2bf(v.y - bf2f(h1)),
                    f2bf(v.z - bf2f(h2)), f2bf(v.w - bf2f(h3))};
        int addr = (r * 512 + c * 2) ^ ((r & 7) << 4);
        *(u16x4*)(Ahi + addr) = hi;
        *(u16x4*)(Alo + addr) = lo;
    }
    __syncthreads();

    const int wave = t >> 6;             // 0..7
    const int lane = t & 63;
    const int lhi  = lane >> 4;          // 0..3
    const int llo  = lane & 15;          // 0..15

    f32x4 acc[4][2];   // [rt][ct]
#pragma unroll
    for (int a = 0; a < 4; ++a)
#pragma unroll
        for (int b = 0; b < 2; ++b) acc[a][b] = (f32x4){0.f, 0.f, 0.f, 0.f};

    const bf16x8* Bp = (const bf16x8*)Bpack;

#pragma unroll
    for (int ks = 0; ks < 8; ++ks) {
        bf16x8 b_hi[2], b_lo[2], a_hi[4], a_lo[4];
#pragma unroll
        for (int ct = 0; ct < 2; ++ct) {
            int ctg = wave * 2 + ct;     // 0..15: this wave's global 16-col tile
            b_hi[ct] = Bp[((ctg * 8 + ks) * 2 + 0) * 64 + lane];
            b_lo[ct] = Bp[((ctg * 8 + ks) * 2 + 1) * 64 + lane];
        }
#pragma unroll
        for (int rt = 0; rt < 4; ++rt) {
            int r = rt * 16 + llo;                       // block-local row 0..63
            int byte = (r * 512 + ks * 64 + lhi * 16) ^ ((r & 7) << 4);
            a_hi[rt] = *(const bf16x8*)(Ahi + byte);
            a_lo[rt] = *(const bf16x8*)(Alo + byte);
        }
#pragma unroll
        for (int rt = 0; rt < 4; ++rt)
#pragma unroll
            for (int ct = 0; ct < 2; ++ct) {
                acc[rt][ct] = __builtin_amdgcn_mfma_f32_16x16x32_bf16(a_hi[rt], b_hi[ct], acc[rt][ct], 0, 0, 0);
                acc[rt][ct] = __builtin_amdgcn_mfma_f32_16x16x32_bf16(a_hi[rt], b_lo[ct], acc[rt][ct], 0, 0, 0);
                acc[rt][ct] = __builtin_amdgcn_mfma_f32_16x16x32_bf16(a_lo[rt], b_hi[ct], acc[rt][ct], 0, 0, 0);
            }
    }

    // ---- epilogue: tanh, *V, reduce over this wave's 32 cols ----
    float s[4][4];
#pragma unroll
    for (int a = 0; a < 4; ++a)
#pragma unroll
        for (int b = 0; b < 4; ++b) s[a][b] = 0.f;

#pragma unroll
    for (int ct = 0; ct < 2; ++ct) {
        int n = wave * 32 + ct * 16 + llo;   // global col (C-frag col = lane&15)
        float qv = qpb[n];
        float vv = Vp[n];
#pragma unroll
        for (int rt = 0; rt < 4; ++rt)
#pragma unroll
            for (int i = 0; i < 4; ++i) {
                float x = acc[rt][ct][i] + qv;
                float e = __expf(2.f * x);
                float th = 1.f - 2.f * __builtin_amdgcn_rcpf(e + 1.f);
                s[rt][i] += th * vv;
            }
    }
    // reduce across the 16 column-lanes of each group
#pragma unroll
    for (int rt = 0; rt < 4; ++rt)
#pragma unroll
        for (int i = 0; i < 4; ++i) {
            float r = s[rt][i];
#pragma unroll
            for (int mask = 1; mask < 16; mask <<= 1) r += __shfl_xor(r, mask, 16);
            s[rt][i] = r;   // sum over this wave's 32 cols, row rt*16+lhi*4+i
        }

    __syncthreads();                 // done with A region; reuse as partial buffer
    float* part = (float*)lds;       // [8 waves][64 rows]
    if (llo == 0) {
#pragma unroll
        for (int rt = 0; rt < 4; ++rt)
#pragma unroll
            for (int i = 0; i < 4; ++i)
                part[wave * 64 + rt * 16 + lhi * 4 + i] = s[rt][i];
    }
    __syncthreads();
    if (t < BM) {
        float r = 0.f;
#pragma unroll
        for (int w = 0; w < 8; ++w) r += part[w * 64 + t];
        out_scores[m0 + t] = r;
    }
}

// ---------------- softmax over seq axis, in-place on d_out ----------------
__global__ __launch_bounds__(256) void softmax_kernel(float* __restrict__ out) {
    const int b = blockIdx.x;
    const int t = threadIdx.x;
    float* row = out + b * SEQ;
    float v[8];
#pragma unroll
    for (int j = 0; j < 8; ++j) v[j] = row[t + j * 256];
    float mx = v[0];
#pragma unroll
    for (int j = 1; j < 8; ++j) mx = fmaxf(mx, v[j]);
#pragma unroll
    for (int off = 1; off < 64; off <<= 1) mx = fmaxf(mx, __shfl_xor(mx, off, 64));
    __shared__ float redm[4], reds[4];
    int lane = t & 63, w = t >> 6;
    if (lane == 0) redm[w] = mx;
    __syncthreads();
    mx = fmaxf(fmaxf(redm[0], redm[1]), fmaxf(redm[2], redm[3]));
    float e[8], sum = 0.f;
#pragma unroll
    for (int j = 0; j < 8; ++j) { e[j] = __expf(v[j] - mx); sum += e[j]; }
#pragma unroll
    for (int off = 1; off < 64; off <<= 1) sum += __shfl_xor(sum, off, 64);
    if (lane == 0) reds[w] = sum;
    __syncthreads();
    float inv = 1.0f / (reds[0] + reds[1] + reds[2] + reds[3]);
#pragma unroll
    for (int j = 0; j < 8; ++j) row[t + j * 256] = e[j] * inv;
}

extern "C" void kernel_launch(void* const* d_in, const int* in_sizes, int n_in,
                              void* d_out, int out_size, void* d_ws, size_t ws_size,
                              hipStream_t stream) {
    const float* q  = (const float*)d_in[0];
    const float* k  = (const float*)d_in[1];
    const float* W1 = (const float*)d_in[2];
    const float* b1 = (const float*)d_in[3];
    const float* W2 = (const float*)d_in[4];
    const float* b2 = (const float*)d_in[5];
    const float* V  = (const float*)d_in[6];
    // d_in[7] = bv: scalar added to every score -> softmax-invariant, skipped.
    float* out = (float*)d_out;

    float* qpb = (float*)d_ws;                                     // 1 KB
    unsigned short* Bpack = (unsigned short*)((char*)d_ws + 1024); // 256 KB

    prep_qpb<<<1, 256, 0, stream>>>(q, W2, b1, b2, qpb);
    prep_bpack<<<32, 256, 0, stream>>>(W1, Bpack);
    fused_main<<<M_TOTAL / BM, 512, 0, stream>>>(k, Bpack, qpb, V, out);
    softmax_kernel<<<NBATCH, 256, 0, stream>>>(out);
}